// Round 17
// baseline (351.842 us; speedup 1.0000x reference)
//
#include <hip/hip_runtime.h>
#include <hip/hip_bf16.h>

typedef __attribute__((ext_vector_type(4)))  float f32x4;
typedef __attribute__((ext_vector_type(16))) float f32x16;
typedef __attribute__((ext_vector_type(8)))  short short8;

#define XROWS 8195            // 3 guard rows + 8192
#define XBATCH (XROWS * 1024) // elems per padded batch

__device__ __forceinline__ short f2bf(float f) {
    union { __hip_bfloat16 h; short s; } u;
    u.h = __float2bfloat16(f);
    return u.s;
}

__device__ __forceinline__ void async16(const void* g, void* l) {
    __builtin_amdgcn_global_load_lds(
        (const __attribute__((address_space(1))) unsigned int*)g,
        (__attribute__((address_space(3))) unsigned int*)l, 16, 0, 0);
}

// ---------------------------------------------------------------------------
// Prepass 1: x fp32 [4][8192][1024] -> Xbf bf16 [4][3+8192][1024], guard=0
// (R2-R14 proven)
// ---------------------------------------------------------------------------
__global__ void x_to_bf16(const float* __restrict__ x,
                          __hip_bfloat16* __restrict__ Xbf) {
    size_t idx = (size_t)blockIdx.x * blockDim.x + threadIdx.x;
    if (idx < 1536) {  // zero 4*3*1024 guard elems
        int b = (int)(idx / 384);
        int r = (int)(idx % 384);
        *reinterpret_cast<short8*>(&Xbf[(size_t)b * XBATCH + r * 8]) =
            (short8){0, 0, 0, 0, 0, 0, 0, 0};
    }
    size_t stride = (size_t)gridDim.x * blockDim.x;
    const size_t nvec = (size_t)4 * 8192 * 1024 / 8;
    for (size_t v = idx; v < nvec; v += stride) {
        size_t e = v * 8;
        int b = (int)(e >> 23);
        size_t rem = e & ((1u << 23) - 1);
        f32x4 lo = *reinterpret_cast<const f32x4*>(x + e);
        f32x4 hi = *reinterpret_cast<const f32x4*>(x + e + 4);
        short8 pk;
        pk[0] = f2bf(lo[0]); pk[1] = f2bf(lo[1]); pk[2] = f2bf(lo[2]); pk[3] = f2bf(lo[3]);
        pk[4] = f2bf(hi[0]); pk[5] = f2bf(hi[1]); pk[6] = f2bf(hi[2]); pk[7] = f2bf(hi[3]);
        *reinterpret_cast<short8*>(&Xbf[(size_t)b * XBATCH + 3 * 1024 + rem]) = pk;
    }
}

// ---------------------------------------------------------------------------
// Prepass 2: kernels [4096][1024] fp32 -> Kt [1024][4096] bf16 (R2-R14 proven)
// ---------------------------------------------------------------------------
__global__ void kconv_transpose(const float* __restrict__ kern,
                                __hip_bfloat16* __restrict__ Kt) {
    __shared__ float tile[32][33];
    int k0 = blockIdx.x << 5;
    int f0 = blockIdx.y << 5;
    int tx = threadIdx.x & 31;
    int ty = threadIdx.x >> 5;
#pragma unroll
    for (int q = 0; q < 4; q++)
        tile[ty + q * 8][tx] = kern[(size_t)(k0 + ty + q * 8) * 1024 + f0 + tx];
    __syncthreads();
#pragma unroll
    for (int q = 0; q < 4; q++)
        Kt[((size_t)(f0 + ty + q * 8) << 12) + k0 + tx] =
            __float2bfloat16(tile[tx][ty + q * 8]);
}

// ---------------------------------------------------------------------------
// Main GEMM — fragment-LANE-major LDS (R8's 0-conflict order), 32x32x16:
//   BM=BN=256, 8 waves (2M x 4N), wave tile 128x64, one barrier/K-tile.
//   LDS 128 KiB = 2-tile dbuf x (A 32KB + B 32KB); region layout
//   [ks(4)][frag(8)][lane(64)][8 elems] -> every ds_read_b128 is
//   uniform + lane*16B (contiguous 1KB/wave, R8-measured 0 conflicts;
//   R15/R16's (l31*32+lh*16) order was a 2-way conflict = 4cyc/read).
//   Staging: global_load_lds per-lane global sources (arbitrary) +
//   linear LDS dest: thread t stages frag=wid, lane-chunk, ks=i from
//   Xbf/Kt directly — no new global layouts. Per tile: aged vmcnt(0)
//   (issued 3/4 tile earlier) + 1 barrier; 4 ks-chunks {6 ds_read ->
//   8 MFMA}; stage T+1 after ks0 reads (depth-1 ledger, R5-proven).
// ---------------------------------------------------------------------------
__global__ void __launch_bounds__(512, 2)
altconv_gemm15(const __hip_bfloat16* __restrict__ Xbf,  // [4][8195][1024]
               const __hip_bfloat16* __restrict__ Kt,   // [1024][4096]
               const float* __restrict__ biases,        // [4][1024]
               float* __restrict__ out) {               // [32768][1024]
    __shared__ alignas(16) __hip_bfloat16 LS[65536];    // 128 KiB

    // bijective XCD swizzle (512 % 8 == 0); nt fastest within an XCD chunk
    int bid  = blockIdx.x;
    int tid2 = (bid & 7) * 64 + (bid >> 3);
    int mt = tid2 >> 2;           // 0..127
    int nt = tid2 & 3;            // 0..3
    int bm0   = mt << 8;
    int batch = bm0 >> 13;
    int srow0 = bm0 & 8191;
    int bn0   = nt << 8;
    const __hip_bfloat16* xb =
        Xbf + (size_t)batch * XBATCH + (size_t)(srow0 + 3) * 1024;

    int t    = threadIdx.x;
    int lane = t & 63;
    int wid  = t >> 6;            // 0..7
    int wr = wid >> 2, wc = wid & 3;
    int l31 = lane & 31, lh = lane >> 5;

    // staging sources: thread stages frag == wid, its lane chunk, ks = i
    //   A elem (frag,lane,ks,e) = Xbf row (wid*32+l31), k = c0 + i*16 + lh*8 + e
    //   B elem = Kt col (bn0 + wid*32+l31), k = T*64 + i*16 + lh*8 + e
    int asrc = (wid * 32 + l31) * 1024 + lh * 8;
    const __hip_bfloat16* bsrc0 =
        Kt + ((size_t)(bn0 + wid * 32 + l31) << 12) + lh * 8;
    int dThr = t * 8;             // elems; chunk u = i*512 + t at u*16B

    // fragment read offsets (elems): slot = ks*8 + frag, addr slot*512+lane*8
    int aOff[4], bOff[2];
#pragma unroll
    for (int mb = 0; mb < 4; mb++) aOff[mb] = (wr * 4 + mb) * 512 + lane * 8;
#pragma unroll
    for (int nb = 0; nb < 2; nb++)
        bOff[nb] = 16384 + (wc * 2 + nb) * 512 + lane * 8;

    f32x16 acc[4][2];
#pragma unroll
    for (int mb = 0; mb < 4; mb++)
#pragma unroll
        for (int nb = 0; nb < 2; nb++)
#pragma unroll
            for (int r = 0; r < 16; r++) acc[mb][nb][r] = 0.f;

#define STAGET(TN) do {                                                       \
        int tap_ = (TN) >> 4;                                                 \
        int c0_  = ((TN) & 15) << 6;                                          \
        const __hip_bfloat16* aS_ = xb - tap_ * 1024 + c0_ + asrc;            \
        const __hip_bfloat16* bS_ = bsrc0 + (TN) * 64;                        \
        int dE_ = ((TN) & 1) << 15;                                           \
        _Pragma("unroll")                                                     \
        for (int i = 0; i < 4; i++)                                           \
            async16(aS_ + i * 16, &LS[dE_ + i * 4096 + dThr]);                \
        _Pragma("unroll")                                                     \
        for (int i = 0; i < 4; i++)                                           \
            async16(bS_ + i * 16, &LS[dE_ + 16384 + i * 4096 + dThr]);        \
    } while (0)

    // prologue: stage tile 0 (8 loads)
    STAGET(0);

    for (int T = 0; T < 64; T++) {
        asm volatile("s_waitcnt vmcnt(0)" ::: "memory");   // aged ~3/4 tile
        __builtin_amdgcn_s_barrier();
        asm volatile("" ::: "memory");
        int base = (T & 1) << 15;
        bool dostage = (T < 63);
#pragma unroll
        for (int ks = 0; ks < 4; ks++) {
            short8 af[4], bf2[2];
#pragma unroll
            for (int mb = 0; mb < 4; mb++)
                af[mb] = *reinterpret_cast<const short8*>(
                    &LS[base + ks * 4096 + aOff[mb]]);
#pragma unroll
            for (int nb = 0; nb < 2; nb++)
                bf2[nb] = *reinterpret_cast<const short8*>(
                    &LS[base + ks * 4096 + bOff[nb]]);
            if (ks == 0 && dostage) STAGET(T + 1);
#pragma unroll
            for (int mb = 0; mb < 4; mb++)
#pragma unroll
                for (int nb = 0; nb < 2; nb++)
                    acc[mb][nb] = __builtin_amdgcn_mfma_f32_32x32x16_bf16(
                        af[mb], bf2[nb], acc[mb][nb], 0, 0, 0);
        }
    }

    // epilogue (R11/R12-verified): col=lane&31, row=(r&3)+8*(r>>2)+4*lh
#pragma unroll
    for (int nb = 0; nb < 2; nb++) {
        int gc = bn0 + wc * 64 + nb * 32 + l31;
        float bsum = biases[gc] + biases[1024 + gc] + biases[2048 + gc] + biases[3072 + gc];
#pragma unroll
        for (int mb = 0; mb < 4; mb++) {
            int rowb = bm0 + wr * 128 + mb * 32 + 4 * lh;
#pragma unroll
            for (int r = 0; r < 16; r++) {
                int row = rowb + (r & 3) + 8 * (r >> 2);
                out[(size_t)row * 1024 + gc] = acc[mb][nb][r] + bsum;
            }
        }
    }
#undef STAGET
}

// ---------------------------------------------------------------------------
// Fallback: plain fp32 (no workspace needed), correct but slow
// ---------------------------------------------------------------------------
__global__ void fallback_conv(const float* __restrict__ x, const float* __restrict__ kern,
                              const float* __restrict__ biases, float* __restrict__ out) {
    __shared__ float xs[1024];
    int row = blockIdx.x;
    int f = (blockIdx.y << 8) + threadIdx.x;
    int batch = row >> 13, s = row & 8191;
    const float* xb = x + (((size_t)batch << 13) << 10);
    float acc = 0.f;
    for (int tap = 0; tap < 4; tap++) {
        int ss = s - tap;
        __syncthreads();
        for (int i = threadIdx.x; i < 1024; i += 256)
            xs[i] = (ss >= 0) ? xb[((size_t)ss << 10) + i] : 0.f;
        __syncthreads();
        const float* kp = kern + ((size_t)tap << 20) + f;
        float a = 0.f;
        for (int d = 0; d < 1024; d++) a += xs[d] * kp[(size_t)d << 10];
        acc += a + biases[(tap << 10) + f];
    }
    out[((size_t)row << 10) + f] = acc;
}

extern "C" void kernel_launch(void* const* d_in, const int* in_sizes, int n_in,
                              void* d_out, int out_size, void* d_ws, size_t ws_size,
                              hipStream_t stream) {
    const float* x      = (const float*)d_in[0];
    const float* kern   = (const float*)d_in[1];
    const float* biases = (const float*)d_in[2];
    float* out = (float*)d_out;

    const size_t xbf_bytes = (size_t)4 * XBATCH * sizeof(__hip_bfloat16); // 67.1 MB
    const size_t kt_bytes  = (size_t)4096 * 1024 * sizeof(__hip_bfloat16); // 8.4 MB

    if (ws_size >= xbf_bytes + kt_bytes) {
        __hip_bfloat16* Xbf = (__hip_bfloat16*)d_ws;
        __hip_bfloat16* Kt  = (__hip_bfloat16*)((char*)d_ws + xbf_bytes);
        x_to_bf16<<<2048, 256, 0, stream>>>(x, Xbf);
        kconv_transpose<<<dim3(128, 32), 256, 0, stream>>>(kern, Kt);
        altconv_gemm15<<<512, 512, 0, stream>>>(Xbf, Kt, biases, out);
    } else {
        fallback_conv<<<dim3(32768, 4), 256, 0, stream>>>(x, kern, biases, out);
    }
}

// Round 18
// 291.811 us; speedup vs baseline: 1.2057x; 1.2057x over previous
//
#include <hip/hip_runtime.h>
#include <hip/hip_bf16.h>

typedef __attribute__((ext_vector_type(4)))  float f32x4;
typedef __attribute__((ext_vector_type(16))) float f32x16;
typedef __attribute__((ext_vector_type(8)))  short short8;

#define XROWS 8195                     // 3 guard rows + 8192
#define KCSTRIDE (XROWS * 16)          // 131120 elems per kc-slab per batch
#define XFB (64 * KCSTRIDE)            // elems per batch

__device__ __forceinline__ short f2bf(float f) {
    union { __hip_bfloat16 h; short s; } u;
    u.h = __float2bfloat16(f);
    return u.s;
}

__device__ __forceinline__ void async16(const void* g, void* l) {
    __builtin_amdgcn_global_load_lds(
        (const __attribute__((address_space(1))) unsigned int*)g,
        (__attribute__((address_space(3))) unsigned int*)l, 16, 0, 0);
}

// ---------------------------------------------------------------------------
// Prepass 1 (R16-verified): x fp32 [4][8192][1024] -> Xf bf16 fragment-major:
//   Xf[batch][kc(64)][row(8195)][16], Xf[b][kc][3+s][e] = x[b][s][kc*16+e],
//   rows 0..2 per (b,kc) are zero guards.
// ---------------------------------------------------------------------------
__global__ void x_to_frag(const float* __restrict__ x,
                          __hip_bfloat16* __restrict__ Xf) {
    if (blockIdx.x == 2048) {   // zero the 4*64*3 guard chunk-rows
        int t0 = threadIdx.x;
#pragma unroll
        for (int k = 0; k < 3; k++) {
            int id = t0 + k * 256;            // 0..767
            int b  = id / 192;
            int rem = id % 192;
            int kc = rem / 3, r = rem % 3;
            size_t o = (size_t)b * XFB + (size_t)kc * KCSTRIDE + r * 16;
            *reinterpret_cast<short8*>(&Xf[o])     = (short8){0,0,0,0,0,0,0,0};
            *reinterpret_cast<short8*>(&Xf[o + 8]) = (short8){0,0,0,0,0,0,0,0};
        }
        return;
    }
    __shared__ __hip_bfloat16 tile[64][264];
    int blk   = blockIdx.x;        // 0..2047
    int bt    = blk >> 9;          // batch (512 blocks/batch)
    int rtile = (blk >> 2) & 127;
    int ktile = blk & 3;
    int r0 = rtile * 64;
    int c0 = ktile * 256;
    int t  = threadIdx.x;
    {   // read: thread covers row r, 64 cols
        int r = t >> 2, q = t & 3;
        const float* src = x + ((size_t)((bt << 13) + r0 + r) << 10) + c0 + q * 64;
#pragma unroll
        for (int j = 0; j < 8; j++) {
            f32x4 lo = *reinterpret_cast<const f32x4*>(src + j * 8);
            f32x4 hi = *reinterpret_cast<const f32x4*>(src + j * 8 + 4);
            short8 pk;
            pk[0] = f2bf(lo[0]); pk[1] = f2bf(lo[1]); pk[2] = f2bf(lo[2]); pk[3] = f2bf(lo[3]);
            pk[4] = f2bf(hi[0]); pk[5] = f2bf(hi[1]); pk[6] = f2bf(hi[2]); pk[7] = f2bf(hi[3]);
            *reinterpret_cast<short8*>(&tile[r][q * 64 + j * 8]) = pk;
        }
    }
    __syncthreads();
    {   // write: thread (kcl = t>>4, rl = t&15) stores rows rl + i*16
        int kcl = t >> 4, rl = t & 15;
        int kc  = ktile * 16 + kcl;
        size_t base = (size_t)bt * XFB + (size_t)kc * KCSTRIDE +
                      (size_t)(3 + r0) * 16;
#pragma unroll
        for (int i = 0; i < 4; i++) {
            int row = rl + i * 16;
            short8 a = *reinterpret_cast<const short8*>(&tile[row][kcl * 16]);
            short8 b = *reinterpret_cast<const short8*>(&tile[row][kcl * 16 + 8]);
            *reinterpret_cast<short8*>(&Xf[base + (size_t)row * 16])     = a;
            *reinterpret_cast<short8*>(&Xf[base + (size_t)row * 16 + 8]) = b;
        }
    }
}

// ---------------------------------------------------------------------------
// Prepass 2 (R16-verified): kernels [4096][1024] fp32 -> Kf fragment-major:
//   Kf[kc(256)][f(1024)][16], Kf[kc][f][e] = kern[kc*16+e][f].
// ---------------------------------------------------------------------------
__global__ void kconv_frag2(const float* __restrict__ kern,
                            __hip_bfloat16* __restrict__ Kf) {
    __shared__ float tile[16][260];
    int kc = blockIdx.x >> 2;      // 0..255
    int f0 = (blockIdx.x & 3) << 8;
    int t  = threadIdx.x;
    {   // read 16 k-rows x 256 f, coalesced
        int r = t >> 4, seg = t & 15;
        const float* src = kern + (size_t)(kc * 16 + r) * 1024 + f0 + seg * 16;
#pragma unroll
        for (int j = 0; j < 4; j++) {
            f32x4 v = *reinterpret_cast<const f32x4*>(src + j * 4);
            tile[r][seg * 16 + j * 4 + 0] = v[0];
            tile[r][seg * 16 + j * 4 + 1] = v[1];
            tile[r][seg * 16 + j * 4 + 2] = v[2];
            tile[r][seg * 16 + j * 4 + 3] = v[3];
        }
    }
    __syncthreads();
    {   // write: thread t = f-local, gather column e=0..15
        short8 a, b;
#pragma unroll
        for (int e = 0; e < 8; e++)  a[e] = f2bf(tile[e][t]);
#pragma unroll
        for (int e = 0; e < 8; e++)  b[e] = f2bf(tile[e + 8][t]);
        size_t base = (size_t)kc * 16384 + (size_t)(f0 + t) * 16;
        *reinterpret_cast<short8*>(&Kf[base])     = a;
        *reinterpret_cast<short8*>(&Kf[base + 8]) = b;
    }
}

// ---------------------------------------------------------------------------
// Main GEMM — all three LDS/DMA constraints satisfied simultaneously:
//   (1) LDS reads uniform+lane*16 (R17: 0 conflicts);
//   (2) linear DMA dest (hardware);
//   (3) DMA sources wave-contiguous 1KB (fragment-major globals, R16).
//   BM=BN=256, 8 waves (2M x 4N), wave tile 128x64, MFMA 32x32x16.
//   LDS 128 KiB = 2-tile dbuf x ([ks(4)][frag(8)][lane(64)][8] A + same B).
//   Thread t stages frag=wid, its lane chunk (l31,lh), ks=i:
//     A src = Xf[kc=c0k+i][g0 + wid*32+l31][lh*8..]  (1KB/wave contiguous)
//     B src = Kf[kc=T*4+i][bn0 + wid*32+l31][lh*8..] (1KB/wave contiguous)
//   Per tile: aged vmcnt(0) + 1 barrier; 4 ks-chunks {6 ds_read -> 8 MFMA};
//   stage T+1 after ks0 reads (depth-1 ledger, R5-proven).
// ---------------------------------------------------------------------------
__global__ void __launch_bounds__(512, 2)
altconv_gemm16(const __hip_bfloat16* __restrict__ Xf,   // fragment-major x
               const __hip_bfloat16* __restrict__ Kf,   // fragment-major K
               const float* __restrict__ biases,        // [4][1024]
               float* __restrict__ out) {               // [32768][1024]
    __shared__ alignas(16) __hip_bfloat16 LS[65536];    // 128 KiB

    // bijective XCD swizzle (512 % 8 == 0); nt fastest within an XCD chunk
    int bid  = blockIdx.x;
    int tid2 = (bid & 7) * 64 + (bid >> 3);
    int mt = tid2 >> 2;           // 0..127
    int nt = tid2 & 3;            // 0..3
    int bm0   = mt << 8;
    int batch = bm0 >> 13;
    int srow0 = bm0 & 8191;
    int bn0   = nt << 8;
    const __hip_bfloat16* xfb = Xf + (size_t)batch * XFB;

    int t    = threadIdx.x;
    int lane = t & 63;
    int wid  = t >> 6;            // 0..7
    int wr = wid >> 2, wc = wid & 3;
    int l31 = lane & 31, lh = lane >> 5;

    // per-thread staging offset: fragment element (frag=wid, l31, lh)
    int aThr = (wid * 32 + l31) * 16 + lh * 8;   // elems within a [.][16] slab
    int dThr = t * 8;                            // linear LDS dest (elems)

    // fragment read offsets: slot = ks*8 + frag, addr = slot*512 + lane*8
    int aOff[4], bOff[2];
#pragma unroll
    for (int mb = 0; mb < 4; mb++) aOff[mb] = (wr * 4 + mb) * 512 + lane * 8;
#pragma unroll
    for (int nb = 0; nb < 2; nb++)
        bOff[nb] = 16384 + (wc * 2 + nb) * 512 + lane * 8;

    f32x16 acc[4][2];
#pragma unroll
    for (int mb = 0; mb < 4; mb++)
#pragma unroll
        for (int nb = 0; nb < 2; nb++)
#pragma unroll
            for (int r = 0; r < 16; r++) acc[mb][nb][r] = 0.f;

#define STAGET(TN) do {                                                       \
        int tap_ = (TN) >> 4;                                                 \
        int c0k_ = ((TN) & 15) << 2;                                          \
        int g0_  = srow0 + 3 - tap_;                                          \
        const __hip_bfloat16* aS_ = xfb + (size_t)g0_ * 16 + aThr;            \
        const __hip_bfloat16* bS_ = Kf + (size_t)bn0 * 16 + aThr;             \
        int dE_ = ((TN) & 1) << 15;                                           \
        _Pragma("unroll")                                                     \
        for (int i = 0; i < 4; i++)                                           \
            async16(aS_ + (size_t)(c0k_ + i) * KCSTRIDE,                      \
                    &LS[dE_ + i * 4096 + dThr]);                              \
        _Pragma("unroll")                                                     \
        for (int i = 0; i < 4; i++)                                           \
            async16(bS_ + (size_t)((TN) * 4 + i) * 16384,                     \
                    &LS[dE_ + 16384 + i * 4096 + dThr]);                      \
    } while (0)

    // prologue: stage tile 0 (8 loads)
    STAGET(0);

    for (int T = 0; T < 64; T++) {
        asm volatile("s_waitcnt vmcnt(0)" ::: "memory");   // aged ~3/4 tile
        __builtin_amdgcn_s_barrier();
        asm volatile("" ::: "memory");
        int base = (T & 1) << 15;
        bool dostage = (T < 63);
#pragma unroll
        for (int ks = 0; ks < 4; ks++) {
            short8 af[4], bf2[2];
#pragma unroll
            for (int mb = 0; mb < 4; mb++)
                af[mb] = *reinterpret_cast<const short8*>(
                    &LS[base + ks * 4096 + aOff[mb]]);
#pragma unroll
            for (int nb = 0; nb < 2; nb++)
                bf2[nb] = *reinterpret_cast<const short8*>(
                    &LS[base + ks * 4096 + bOff[nb]]);
            if (ks == 0 && dostage) STAGET(T + 1);
#pragma unroll
            for (int mb = 0; mb < 4; mb++)
#pragma unroll
                for (int nb = 0; nb < 2; nb++)
                    acc[mb][nb] = __builtin_amdgcn_mfma_f32_32x32x16_bf16(
                        af[mb], bf2[nb], acc[mb][nb], 0, 0, 0);
        }
    }

    // epilogue (R11/R12-verified): col=lane&31, row=(r&3)+8*(r>>2)+4*lh
#pragma unroll
    for (int nb = 0; nb < 2; nb++) {
        int gc = bn0 + wc * 64 + nb * 32 + l31;
        float bsum = biases[gc] + biases[1024 + gc] + biases[2048 + gc] + biases[3072 + gc];
#pragma unroll
        for (int mb = 0; mb < 4; mb++) {
            int rowb = bm0 + wr * 128 + mb * 32 + 4 * lh;
#pragma unroll
            for (int r = 0; r < 16; r++) {
                int row = rowb + (r & 3) + 8 * (r >> 2);
                out[(size_t)row * 1024 + gc] = acc[mb][nb][r] + bsum;
            }
        }
    }
#undef STAGET
}

// ---------------------------------------------------------------------------
// Fallback: plain fp32 (no workspace needed), correct but slow
// ---------------------------------------------------------------------------
__global__ void fallback_conv(const float* __restrict__ x, const float* __restrict__ kern,
                              const float* __restrict__ biases, float* __restrict__ out) {
    __shared__ float xs[1024];
    int row = blockIdx.x;
    int f = (blockIdx.y << 8) + threadIdx.x;
    int batch = row >> 13, s = row & 8191;
    const float* xb = x + (((size_t)batch << 13) << 10);
    float acc = 0.f;
    for (int tap = 0; tap < 4; tap++) {
        int ss = s - tap;
        __syncthreads();
        for (int i = threadIdx.x; i < 1024; i += 256)
            xs[i] = (ss >= 0) ? xb[((size_t)ss << 10) + i] : 0.f;
        __syncthreads();
        const float* kp = kern + ((size_t)tap << 20) + f;
        float a = 0.f;
        for (int d = 0; d < 1024; d++) a += xs[d] * kp[(size_t)d << 10];
        acc += a + biases[(tap << 10) + f];
    }
    out[((size_t)row << 10) + f] = acc;
}

extern "C" void kernel_launch(void* const* d_in, const int* in_sizes, int n_in,
                              void* d_out, int out_size, void* d_ws, size_t ws_size,
                              hipStream_t stream) {
    const float* x      = (const float*)d_in[0];
    const float* kern   = (const float*)d_in[1];
    const float* biases = (const float*)d_in[2];
    float* out = (float*)d_out;

    const size_t xf_bytes = (size_t)4 * XFB * sizeof(__hip_bfloat16);       // 67.1 MB
    const size_t kf_bytes = (size_t)4096 * 1024 * sizeof(__hip_bfloat16);   // 8.4 MB

    if (ws_size >= xf_bytes + kf_bytes) {
        __hip_bfloat16* Xf = (__hip_bfloat16*)d_ws;
        __hip_bfloat16* Kf = (__hip_bfloat16*)((char*)d_ws + xf_bytes);
        x_to_frag<<<2049, 256, 0, stream>>>(x, Xf);
        kconv_frag2<<<1024, 256, 0, stream>>>(kern, Kf);
        altconv_gemm16<<<512, 512, 0, stream>>>(Xf, Kf, biases, out);
    } else {
        fallback_conv<<<dim3(32768, 4), 256, 0, stream>>>(x, kern, biases, out);
    }
}

// Round 19
// 260.642 us; speedup vs baseline: 1.3499x; 1.1196x over previous
//
#include <hip/hip_runtime.h>
#include <hip/hip_bf16.h>

typedef __attribute__((ext_vector_type(4))) float f32x4;
typedef __attribute__((ext_vector_type(8))) short short8;

#define XROWS 8195            // 3 guard rows + 8192
#define XBATCH (XROWS * 1024) // elems per padded batch

__device__ __forceinline__ short f2bf(float f) {
    union { __hip_bfloat16 h; short s; } u;
    u.h = __float2bfloat16(f);
    return u.s;
}

__device__ __forceinline__ void async16(const void* g, void* l) {
    __builtin_amdgcn_global_load_lds(
        (const __attribute__((address_space(1))) unsigned int*)g,
        (__attribute__((address_space(3))) unsigned int*)l, 16, 0, 0);
}

// ---------------------------------------------------------------------------
// Fused prepass (bodies verbatim from R14's two proven kernels):
//   blocks 0..2047:    x fp32 [4][8192][1024] -> Xbf bf16 [4][3+8192][1024]
//   blocks 2048..6143: kernels [4096][1024] fp32 -> Kt [1024][4096] bf16
// One launch instead of two; the small transpose overlaps the HBM-bound
// conversion. No intra-block divergence (branch on blockIdx only).
// ---------------------------------------------------------------------------
__global__ void __launch_bounds__(256)
prepass_fused(const float* __restrict__ x, __hip_bfloat16* __restrict__ Xbf,
              const float* __restrict__ kern, __hip_bfloat16* __restrict__ Kt) {
    int blk = blockIdx.x;
    if (blk < 2048) {
        size_t idx = (size_t)blk * 256 + threadIdx.x;
        if (idx < 1536) {  // zero 4*3*1024 guard elems
            int b = (int)(idx / 384);
            int r = (int)(idx % 384);
            *reinterpret_cast<short8*>(&Xbf[(size_t)b * XBATCH + r * 8]) =
                (short8){0, 0, 0, 0, 0, 0, 0, 0};
        }
        const size_t stride = (size_t)2048 * 256;
        const size_t nvec = (size_t)4 * 8192 * 1024 / 8;
        for (size_t v = idx; v < nvec; v += stride) {
            size_t e = v * 8;
            int b = (int)(e >> 23);
            size_t rem = e & ((1u << 23) - 1);
            f32x4 lo = *reinterpret_cast<const f32x4*>(x + e);
            f32x4 hi = *reinterpret_cast<const f32x4*>(x + e + 4);
            short8 pk;
            pk[0] = f2bf(lo[0]); pk[1] = f2bf(lo[1]); pk[2] = f2bf(lo[2]); pk[3] = f2bf(lo[3]);
            pk[4] = f2bf(hi[0]); pk[5] = f2bf(hi[1]); pk[6] = f2bf(hi[2]); pk[7] = f2bf(hi[3]);
            *reinterpret_cast<short8*>(&Xbf[(size_t)b * XBATCH + 3 * 1024 + rem]) = pk;
        }
    } else {
        __shared__ float tile[32][33];
        int b2 = blk - 2048;           // 0..4095
        int k0 = (b2 & 127) << 5;      // 128 k-tiles
        int f0 = (b2 >> 7) << 5;       // 32 f-tiles
        int tx = threadIdx.x & 31;
        int ty = threadIdx.x >> 5;
#pragma unroll
        for (int q = 0; q < 4; q++)
            tile[ty + q * 8][tx] =
                kern[(size_t)(k0 + ty + q * 8) * 1024 + f0 + tx];
        __syncthreads();
#pragma unroll
        for (int q = 0; q < 4; q++)
            Kt[((size_t)(f0 + ty + q * 8) << 12) + k0 + tx] =
                __float2bfloat16(tile[tx][ty + q * 8]);
    }
}

// ---------------------------------------------------------------------------
// Main GEMM — R14 verbatim (best measured: 225.5us dispatch, MfmaUtil 56%,
//   0 bank conflicts). 256^2 tile, BK=64, 8 waves (2M x 4N), wave tile
//   128x64, 512 threads. LDS 128 KiB = 2-tile dbuf x (A 32KB + B 32KB).
//   8 phases / 2 K-tiles; phase = one C-quadrant (h,ks): 4 A ds_reads
//   (+4 B on ks-change), 1 half-tile stage (4 async16), 1 barrier, 16
//   MFMA (no setprio — m190: negative on barrier-lockstep). Counted
//   vmcnt(4) at phases 1 & 5 only; never 0 in the main loop.
//   XOR swizzle byte^=((row&7)<<4); linear DMA dest + inverse-swizzled
//   source (rule 21). Stage halves match quadrant row sets (race-free).
// ---------------------------------------------------------------------------
__global__ void __launch_bounds__(512, 2)
altconv_gemm12(const __hip_bfloat16* __restrict__ Xbf,  // [4][8195][1024]
               const __hip_bfloat16* __restrict__ Kt,   // [1024][4096]
               const float* __restrict__ biases,        // [4][1024]
               float* __restrict__ out) {               // [32768][1024]
    __shared__ alignas(16) __hip_bfloat16 LS[65536];   // 128 KiB

    // bijective XCD swizzle (512 % 8 == 0); nt fastest within an XCD chunk
    int bid  = blockIdx.x;
    int tid2 = (bid & 7) * 64 + (bid >> 3);
    int mt = tid2 >> 2;           // 0..127
    int nt = tid2 & 3;            // 0..3
    int bm0   = mt << 8;
    int batch = bm0 >> 13;
    int srow0 = bm0 & 8191;
    int bn0   = nt << 8;
    const __hip_bfloat16* xb = Xbf + (size_t)batch * XBATCH;

    int t    = threadIdx.x;
    int lane = t & 63;
    int wid  = t >> 6;            // 0..7
    int wr = wid >> 2, wc = wid & 3;
    int frr = lane & 15, q = lane >> 4;
    int swz = (frr & 7) << 4;

    // fragment read elem offsets (row pitch 64 elems = 128B)
    int aRd[2][4][2], bRd[4][2];
#pragma unroll
    for (int h = 0; h < 2; h++)
#pragma unroll
        for (int m = 0; m < 4; m++) {
            int row = wr * 128 + h * 64 + m * 16 + frr;
#pragma unroll
            for (int ks = 0; ks < 2; ks++)
                aRd[h][m][ks] = row * 64 + (((ks * 64 + (q << 4)) ^ swz) >> 1);
        }
#pragma unroll
    for (int n = 0; n < 4; n++) {
        int row = wc * 64 + n * 16 + frr;
#pragma unroll
        for (int ks = 0; ks < 2; ks++)
            bRd[n][ks] = row * 64 + (((ks * 64 + (q << 4)) ^ swz) >> 1);
    }

    // staging precompute (per thread, 2 chunks per half):
    int srcA[2], dstA[2], srcB[2], dstB[2];
#pragma unroll
    for (int ld = 0; ld < 2; ld++) {
        int u  = ld * 512 + t;
        int rr = u >> 3;
        int c  = u & 7;
        int growA = (rr < 64) ? rr : rr + 64;           // HF=0 quadrant rows
        dstA[ld] = growA * 8 + c;
        srcA[ld] = growA * 1024 + ((c ^ (growA & 7)) * 8);
        dstB[ld] = rr * 8 + c;
        srcB[ld] = rr * 4096 + ((c ^ (rr & 7)) * 8);
    }

    f32x4 acc[2][4][4];
#pragma unroll
    for (int h = 0; h < 2; h++)
#pragma unroll
        for (int m = 0; m < 4; m++)
#pragma unroll
            for (int n = 0; n < 4; n++) acc[h][m][n] = (f32x4){0.f, 0.f, 0.f, 0.f};

#define STAGEH(T, HF) do {                                                    \
        int tap_ = (T) >> 4;                                                  \
        int d0_  = ((T) & 15) << 6;                                           \
        int pA_  = ((T) & 1) << 15;  /* buf elem base: 0 or 32768 */          \
        const __hip_bfloat16* xT_ =                                           \
            xb + (size_t)(srow0 + 3 - tap_) * 1024 + d0_ + (HF) * 65536;      \
        const __hip_bfloat16* bT_ =                                           \
            Kt + (((size_t)(bn0 + (HF) * 128)) << 12) + (T) * 64;             \
        _Pragma("unroll")                                                     \
        for (int ld = 0; ld < 2; ld++)                                        \
            async16(xT_ + srcA[ld], &LS[pA_ + (dstA[ld] + (HF) * 512) * 8]);  \
        _Pragma("unroll")                                                     \
        for (int ld = 0; ld < 2; ld++)                                        \
            async16(bT_ + srcB[ld],                                           \
                    &LS[pA_ + 16384 + (dstB[ld] + (HF) * 1024) * 8]);         \
    } while (0)

    short8 bfr[4];

    // R7-order phase: [wait] -> barrier -> reads -> stage -> 16 MFMA
#define PH(P, H, KS, RB, WAIT, STG, STGT, STGHF) do {                         \
        if ((WAIT) == 4) asm volatile("s_waitcnt vmcnt(4)" ::: "memory");     \
        else if ((WAIT) == 0) asm volatile("s_waitcnt vmcnt(0)" ::: "memory");\
        __builtin_amdgcn_s_barrier();                                         \
        asm volatile("" ::: "memory");                                        \
        short8 af[4];                                                         \
        _Pragma("unroll")                                                     \
        for (int m = 0; m < 4; m++)                                           \
            af[m] = *reinterpret_cast<const short8*>(                         \
                &LS[((P) << 15) + aRd[H][m][KS]]);                            \
        if (RB) {                                                             \
            _Pragma("unroll")                                                 \
            for (int n = 0; n < 4; n++)                                       \
                bfr[n] = *reinterpret_cast<const short8*>(                    \
                    &LS[((P) << 15) + 16384 + bRd[n][KS]]);                   \
        }                                                                     \
        if (STG) STAGEH(STGT, STGHF);                                         \
        _Pragma("unroll")                                                     \
        for (int m = 0; m < 4; m++)                                           \
            _Pragma("unroll")                                                 \
            for (int n = 0; n < 4; n++)                                       \
                acc[H][m][n] = __builtin_amdgcn_mfma_f32_16x16x32_bf16(       \
                    af[m], bfr[n], acc[H][m][n], 0, 0, 0);                    \
    } while (0)

    // prologue: T0 both halves, T1 half0 (12 loads in flight)
    STAGEH(0, 0);
    STAGEH(0, 1);
    STAGEH(1, 0);

    for (int I = 0; I < 31; ++I) {
        int T1 = 2 * I + 1, T2 = 2 * I + 2, T3 = 2 * I + 3;
        PH(0, 0, 0, 1, 4, 1, T1, 1);   // wait T0-class done; stage odd.HF1
        PH(0, 1, 0, 0, -1, 0, 0, 0);
        PH(0, 0, 1, 1, -1, 0, 0, 0);
        PH(0, 1, 1, 0, -1, 1, T2, 0);  // even+2 half0 (rows free after ph3)
        PH(1, 0, 0, 1, 4, 1, T2, 1);   // wait odd done; even+2 half1
        PH(1, 1, 0, 0, -1, 0, 0, 0);
        PH(1, 0, 1, 1, -1, 0, 0, 0);
        PH(1, 1, 1, 0, -1, 1, T3, 0);  // odd+2 half0
    }
    // epilogue super: tiles 62 (buf0), 63 (buf1); finish 63.HF1, then drain
    PH(0, 0, 0, 1, 4, 1, 63, 1);
    PH(0, 1, 0, 0, -1, 0, 0, 0);
    PH(0, 0, 1, 1, -1, 0, 0, 0);
    PH(0, 1, 1, 0, -1, 0, 0, 0);
    PH(1, 0, 0, 1, 0, 0, 0, 0);        // vmcnt(0): tile 63 fully landed
    PH(1, 1, 0, 0, -1, 0, 0, 0);
    PH(1, 0, 1, 1, -1, 0, 0, 0);
    PH(1, 1, 1, 0, -1, 0, 0, 0);

    // epilogue: C/D layout col=lane&15, row=(lane>>4)*4+j  [m89]
    int fr   = lane & 15;
    int rowg = (lane >> 4) << 2;
#pragma unroll
    for (int n = 0; n < 4; n++) {
        int gc = bn0 + wc * 64 + n * 16 + fr;
        float bsum = biases[gc] + biases[1024 + gc] + biases[2048 + gc] + biases[3072 + gc];
#pragma unroll
        for (int h = 0; h < 2; h++)
#pragma unroll
            for (int m = 0; m < 4; m++) {
                size_t gr = (size_t)(bm0 + wr * 128 + h * 64 + m * 16 + rowg);
#pragma unroll
                for (int j = 0; j < 4; j++) {
                    out[(gr + j) * 1024 + gc] = acc[h][m][n][j] + bsum;
                }
            }
    }
#undef STAGEH
#undef PH
}

// ---------------------------------------------------------------------------
// Fallback: plain fp32 (no workspace needed), correct but slow
// ---------------------------------------------------------------------------
__global__ void fallback_conv(const float* __restrict__ x, const float* __restrict__ kern,
                              const float* __restrict__ biases, float* __restrict__ out) {
    __shared__ float xs[1024];
    int row = blockIdx.x;
    int f = (blockIdx.y << 8) + threadIdx.x;
    int batch = row >> 13, s = row & 8191;
    const float* xb = x + (((size_t)batch << 13) << 10);
    float acc = 0.f;
    for (int tap = 0; tap < 4; tap++) {
        int ss = s - tap;
        __syncthreads();
        for (int i = threadIdx.x; i < 1024; i += 256)
            xs[i] = (ss >= 0) ? xb[((size_t)ss << 10) + i] : 0.f;
        __syncthreads();
        const float* kp = kern + ((size_t)tap << 20) + f;
        float a = 0.f;
        for (int d = 0; d < 1024; d++) a += xs[d] * kp[(size_t)d << 10];
        acc += a + biases[(tap << 10) + f];
    }
    out[((size_t)row << 10) + f] = acc;
}

extern "C" void kernel_launch(void* const* d_in, const int* in_sizes, int n_in,
                              void* d_out, int out_size, void* d_ws, size_t ws_size,
                              hipStream_t stream) {
    const float* x      = (const float*)d_in[0];
    const float* kern   = (const float*)d_in[1];
    const float* biases = (const float*)d_in[2];
    float* out = (float*)d_out;

    const size_t xbf_bytes = (size_t)4 * XBATCH * sizeof(__hip_bfloat16); // 67.1 MB
    const size_t kt_bytes  = (size_t)4096 * 1024 * sizeof(__hip_bfloat16); // 8.4 MB

    if (ws_size >= xbf_bytes + kt_bytes) {
        __hip_bfloat16* Xbf = (__hip_bfloat16*)d_ws;
        __hip_bfloat16* Kt  = (__hip_bfloat16*)((char*)d_ws + xbf_bytes);
        prepass_fused<<<6144, 256, 0, stream>>>(x, Xbf, kern, Kt);
        altconv_gemm12<<<512, 512, 0, stream>>>(Xbf, Kt, biases, out);
    } else {
        fallback_conv<<<dim3(32768, 4), 256, 0, stream>>>(x, kern, biases, out);
    }
}

// Round 20
// 257.496 us; speedup vs baseline: 1.3664x; 1.0122x over previous
//
#include <hip/hip_runtime.h>
#include <hip/hip_bf16.h>

typedef __attribute__((ext_vector_type(4))) float f32x4;
typedef __attribute__((ext_vector_type(8))) short short8;

#define XROWS 8195            // 3 guard rows + 8192
#define XBATCH (XROWS * 1024) // elems per padded batch

__device__ __forceinline__ short f2bf(float f) {
    union { __hip_bfloat16 h; short s; } u;
    u.h = __float2bfloat16(f);
    return u.s;
}

__device__ __forceinline__ void async16(const void* g, void* l) {
    __builtin_amdgcn_global_load_lds(
        (const __attribute__((address_space(1))) unsigned int*)g,
        (__attribute__((address_space(3))) unsigned int*)l, 16, 0, 0);
}

// ---------------------------------------------------------------------------
// Fused prepass (R19-verified):
//   blocks 0..2047:    x fp32 [4][8192][1024] -> Xbf bf16 [4][3+8192][1024]
//   blocks 2048..6143: kernels [4096][1024] fp32 -> Kt [1024][4096] bf16
// ---------------------------------------------------------------------------
__global__ void __launch_bounds__(256)
prepass_fused(const float* __restrict__ x, __hip_bfloat16* __restrict__ Xbf,
              const float* __restrict__ kern, __hip_bfloat16* __restrict__ Kt) {
    int blk = blockIdx.x;
    if (blk < 2048) {
        size_t idx = (size_t)blk * 256 + threadIdx.x;
        if (idx < 1536) {  // zero 4*3*1024 guard elems
            int b = (int)(idx / 384);
            int r = (int)(idx % 384);
            *reinterpret_cast<short8*>(&Xbf[(size_t)b * XBATCH + r * 8]) =
                (short8){0, 0, 0, 0, 0, 0, 0, 0};
        }
        const size_t stride = (size_t)2048 * 256;
        const size_t nvec = (size_t)4 * 8192 * 1024 / 8;
        for (size_t v = idx; v < nvec; v += stride) {
            size_t e = v * 8;
            int b = (int)(e >> 23);
            size_t rem = e & ((1u << 23) - 1);
            f32x4 lo = *reinterpret_cast<const f32x4*>(x + e);
            f32x4 hi = *reinterpret_cast<const f32x4*>(x + e + 4);
            short8 pk;
            pk[0] = f2bf(lo[0]); pk[1] = f2bf(lo[1]); pk[2] = f2bf(lo[2]); pk[3] = f2bf(lo[3]);
            pk[4] = f2bf(hi[0]); pk[5] = f2bf(hi[1]); pk[6] = f2bf(hi[2]); pk[7] = f2bf(hi[3]);
            *reinterpret_cast<short8*>(&Xbf[(size_t)b * XBATCH + 3 * 1024 + rem]) = pk;
        }
    } else {
        __shared__ float tile[32][33];
        int b2 = blk - 2048;           // 0..4095
        int k0 = (b2 & 127) << 5;      // 128 k-tiles
        int f0 = (b2 >> 7) << 5;       // 32 f-tiles
        int tx = threadIdx.x & 31;
        int ty = threadIdx.x >> 5;
#pragma unroll
        for (int q = 0; q < 4; q++)
            tile[ty + q * 8][tx] =
                kern[(size_t)(k0 + ty + q * 8) * 1024 + f0 + tx];
        __syncthreads();
#pragma unroll
        for (int q = 0; q < 4; q++)
            Kt[((size_t)(f0 + ty + q * 8) << 12) + k0 + tx] =
                __float2bfloat16(tile[tx][ty + q * 8]);
    }
}

// ---------------------------------------------------------------------------
// Main GEMM — R14 structure with m201-style 2-loads-per-phase stage spread:
//   256^2 tile, BK=64, 8 waves (2M x 4N), wave tile 128x64, 512 threads.
//   LDS 128 KiB = 2-tile dbuf x (A 32KB + B 32KB). 8 phases / 2 K-tiles;
//   phase = one C-quadrant (h,ks): 4 A ds_reads (+4 B on ks-change),
//   <=2 async16 stage loads (smooth VMEM issue vs R14's 4-load bursts),
//   1 barrier, 16 MFMA (no setprio - m190). Counted waits: ph1 vmcnt(4),
//   ph5 vmcnt(2); never 0 in the main loop. Stage ledger (re-derived,
//   provably race-free): ph1=O.H1a ph2=O.H1b ph4=E2.H0a ph5=E2.H0b
//   ph6=E2.H1a ph7=E2.H1b ph8=O2.H0ab — every write >=1 barrier after
//   its region's last read. XOR swizzle byte^=((row&7)<<4) (0 conflicts
//   R3-R19); linear DMA dest + inverse-swizzled source (rule 21).
// ---------------------------------------------------------------------------
__global__ void __launch_bounds__(512, 2)
altconv_gemm17(const __hip_bfloat16* __restrict__ Xbf,  // [4][8195][1024]
               const __hip_bfloat16* __restrict__ Kt,   // [1024][4096]
               const float* __restrict__ biases,        // [4][1024]
               float* __restrict__ out) {               // [32768][1024]
    __shared__ alignas(16) __hip_bfloat16 LS[65536];   // 128 KiB

    // bijective XCD swizzle (512 % 8 == 0); nt fastest within an XCD chunk
    int bid  = blockIdx.x;
    int tid2 = (bid & 7) * 64 + (bid >> 3);
    int mt = tid2 >> 2;           // 0..127
    int nt = tid2 & 3;            // 0..3
    int bm0   = mt << 8;
    int batch = bm0 >> 13;
    int srow0 = bm0 & 8191;
    int bn0   = nt << 8;
    const __hip_bfloat16* xb = Xbf + (size_t)batch * XBATCH;

    int t    = threadIdx.x;
    int lane = t & 63;
    int wid  = t >> 6;            // 0..7
    int wr = wid >> 2, wc = wid & 3;
    int frr = lane & 15, q = lane >> 4;
    int swz = (frr & 7) << 4;

    // fragment read elem offsets (row pitch 64 elems = 128B)
    int aRd[2][4][2], bRd[4][2];
#pragma unroll
    for (int h = 0; h < 2; h++)
#pragma unroll
        for (int m = 0; m < 4; m++) {
            int row = wr * 128 + h * 64 + m * 16 + frr;
#pragma unroll
            for (int ks = 0; ks < 2; ks++)
                aRd[h][m][ks] = row * 64 + (((ks * 64 + (q << 4)) ^ swz) >> 1);
        }
#pragma unroll
    for (int n = 0; n < 4; n++) {
        int row = wc * 64 + n * 16 + frr;
#pragma unroll
        for (int ks = 0; ks < 2; ks++)
            bRd[n][ks] = row * 64 + (((ks * 64 + (q << 4)) ^ swz) >> 1);
    }

    // staging precompute (per thread, 2 chunks per half):
    int srcA[2], dstA[2], srcB[2], dstB[2];
#pragma unroll
    for (int ld = 0; ld < 2; ld++) {
        int u  = ld * 512 + t;
        int rr = u >> 3;
        int c  = u & 7;
        int growA = (rr < 64) ? rr : rr + 64;           // HF=0 quadrant rows
        dstA[ld] = growA * 8 + c;
        srcA[ld] = growA * 1024 + ((c ^ (growA & 7)) * 8);
        dstB[ld] = rr * 8 + c;
        srcB[ld] = rr * 4096 + ((c ^ (rr & 7)) * 8);
    }

    f32x4 acc[2][4][4];
#pragma unroll
    for (int h = 0; h < 2; h++)
#pragma unroll
        for (int m = 0; m < 4; m++)
#pragma unroll
            for (int n = 0; n < 4; n++) acc[h][m][n] = (f32x4){0.f, 0.f, 0.f, 0.f};

#define STAGEA(T, HF) do {                                                    \
        int tap_ = (T) >> 4;                                                  \
        int d0_  = ((T) & 15) << 6;                                           \
        int pA_  = ((T) & 1) << 15;                                           \
        const __hip_bfloat16* xT_ =                                           \
            xb + (size_t)(srow0 + 3 - tap_) * 1024 + d0_ + (HF) * 65536;      \
        _Pragma("unroll")                                                     \
        for (int ld = 0; ld < 2; ld++)                                        \
            async16(xT_ + srcA[ld], &LS[pA_ + (dstA[ld] + (HF) * 512) * 8]);  \
    } while (0)

#define STAGEB(T, HF) do {                                                    \
        int pA_  = ((T) & 1) << 15;                                           \
        const __hip_bfloat16* bT_ =                                           \
            Kt + (((size_t)(bn0 + (HF) * 128)) << 12) + (T) * 64;             \
        _Pragma("unroll")                                                     \
        for (int ld = 0; ld < 2; ld++)                                        \
            async16(bT_ + srcB[ld],                                           \
                    &LS[pA_ + 16384 + (dstB[ld] + (HF) * 1024) * 8]);         \
    } while (0)

    short8 bfr[4];

    // phase: [wait] -> barrier -> reads -> stage(<=2 loads) -> 16 MFMA
#define PH(P, H, KS, RB, WAIT, STGSTMT) do {                                  \
        if ((WAIT) == 4) asm volatile("s_waitcnt vmcnt(4)" ::: "memory");     \
        else if ((WAIT) == 2) asm volatile("s_waitcnt vmcnt(2)" ::: "memory");\
        else if ((WAIT) == 0) asm volatile("s_waitcnt vmcnt(0)" ::: "memory");\
        __builtin_amdgcn_s_barrier();                                         \
        asm volatile("" ::: "memory");                                        \
        short8 af[4];                                                         \
        _Pragma("unroll")                                                     \
        for (int m = 0; m < 4; m++)                                           \
            af[m] = *reinterpret_cast<const short8*>(                         \
                &LS[((P) << 15) + aRd[H][m][KS]]);                            \
        if (RB) {                                                             \
            _Pragma("unroll")                                                 \
            for (int n = 0; n < 4; n++)                                       \
                bfr[n] = *reinterpret_cast<const short8*>(                    \
                    &LS[((P) << 15) + 16384 + bRd[n][KS]]);                   \
        }                                                                     \
        STGSTMT;                                                              \
        _Pragma("unroll")                                                     \
        for (int m = 0; m < 4; m++)                                           \
            _Pragma("unroll")                                                 \
            for (int n = 0; n < 4; n++)                                       \
                acc[H][m][n] = __builtin_amdgcn_mfma_f32_16x16x32_bf16(       \
                    af[m], bfr[n], acc[H][m][n], 0, 0, 0);                    \
    } while (0)

    // prologue: T0 both halves, T1 half0 (12 loads in flight)
    STAGEA(0, 0); STAGEB(0, 0);
    STAGEA(0, 1); STAGEB(0, 1);
    STAGEA(1, 0); STAGEB(1, 0);

    for (int I = 0; I < 31; ++I) {
        int T1 = 2 * I + 1, T2 = 2 * I + 2, T3 = 2 * I + 3;
        PH(0, 0, 0, 1,  4, STAGEA(T1, 1));   // wait E done; stage O.H1 A-half
        PH(0, 1, 0, 0, -1, STAGEB(T1, 1));   // O.H1 B-half
        PH(0, 0, 1, 1, -1, ;);
        PH(0, 1, 1, 0, -1, STAGEA(T2, 0));   // E2.H0 A (A-HF0 last read ph3)
        PH(1, 0, 0, 1,  2, STAGEB(T2, 0));   // wait O done (drain 8 of 10)
        PH(1, 1, 0, 0, -1, STAGEA(T2, 1));   // E2.H1 A (A-HF1 last read ph4)
        PH(1, 0, 1, 1, -1, STAGEB(T2, 1));
        PH(1, 1, 1, 0, -1, { STAGEA(T3, 0); STAGEB(T3, 0); });
    }
    // epilogue super: tiles 62 (buf0), 63 (buf1); stage 63.H1, then drain
    PH(0, 0, 0, 1,  4, STAGEA(63, 1));
    PH(0, 1, 0, 0, -1, STAGEB(63, 1));
    PH(0, 0, 1, 1, -1, ;);
    PH(0, 1, 1, 0, -1, ;);
    PH(1, 0, 0, 1,  0, ;);                   // vmcnt(0): tile 63 fully landed
    PH(1, 1, 0, 0, -1, ;);
    PH(1, 0, 1, 1, -1, ;);
    PH(1, 1, 1, 0, -1, ;);

    // epilogue: C/D layout col=lane&15, row=(lane>>4)*4+j  [m89]
    int fr   = lane & 15;
    int rowg = (lane >> 4) << 2;
#pragma unroll
    for (int n = 0; n < 4; n++) {
        int gc = bn0 + wc * 64 + n * 16 + fr;
        float bsum = biases[gc] + biases[1024 + gc] + biases[2048 + gc] + biases[3072 + gc];
#pragma unroll
        for (int h = 0; h < 2; h++)
#pragma unroll
            for (int m = 0; m < 4; m++) {
                size_t gr = (size_t)(bm0 + wr * 128 + h * 64 + m * 16 + rowg);
#pragma unroll
                for (int j = 0; j < 4; j++) {
                    out[(gr + j) * 1024 + gc] = acc[h][m][n][j] + bsum;
                }
            }
    }
#undef STAGEA
#undef STAGEB
#undef PH
}

// ---------------------------------------------------------------------------
// Fallback: plain fp32 (no workspace needed), correct but slow
// ---------------------------------------------------------------------------
__global__ void fallback_conv(const float* __restrict__ x, const float* __restrict__ kern,
                              const float* __restrict__ biases, float* __restrict__ out) {
    __shared__ float xs[1024];
    int row = blockIdx.x;
    int f = (blockIdx.y << 8) + threadIdx.x;
    int batch = row >> 13, s = row & 8191;
    const float* xb = x + (((size_t)batch << 13) << 10);
    float acc = 0.f;
    for (int tap = 0; tap < 4; tap++) {
        int ss = s - tap;
        __syncthreads();
        for (int i = threadIdx.x; i < 1024; i += 256)
            xs[i] = (ss >= 0) ? xb[((size_t)ss << 10) + i] : 0.f;
        __syncthreads();
        const float* kp = kern + ((size_t)tap << 20) + f;
        float a = 0.f;
        for (int d = 0; d < 1024; d++) a += xs[d] * kp[(size_t)d << 10];
        acc += a + biases[(tap << 10) + f];
    }
    out[((size_t)row << 10) + f] = acc;
}

extern "C" void kernel_launch(void* const* d_in, const int* in_sizes, int n_in,
                              void* d_out, int out_size, void* d_ws, size_t ws_size,
                              hipStream_t stream) {
    const float* x      = (const float*)d_in[0];
    const float* kern   = (const float*)d_in[1];
    const float* biases = (const float*)d_in[2];
    float* out = (float*)d_out;

    const size_t xbf_bytes = (size_t)4 * XBATCH * sizeof(__hip_bfloat16); // 67.1 MB
    const size_t kt_bytes  = (size_t)4096 * 1024 * sizeof(__hip_bfloat16); // 8.4 MB

    if (ws_size >= xbf_bytes + kt_bytes) {
        __hip_bfloat16* Xbf = (__hip_bfloat16*)d_ws;
        __hip_bfloat16* Kt  = (__hip_bfloat16*)((char*)d_ws + xbf_bytes);
        prepass_fused<<<6144, 256, 0, stream>>>(x, Xbf, kern, Kt);
        altconv_gemm17<<<512, 512, 0, stream>>>(Xbf, Kt, biases, out);
    } else {
        fallback_conv<<<dim3(32768, 4), 256, 0, stream>>>(x, kern, biases, out);
    }
}